// Round 1
// baseline (374.019 us; speedup 1.0000x reference)
//
#include <hip/hip_runtime.h>
#include <hip/hip_bf16.h>
#include <cmath>

typedef __bf16 bf16_t;
typedef __bf16 bf16x8 __attribute__((ext_vector_type(8)));
typedef __bf16 bf16x4 __attribute__((ext_vector_type(4)));
typedef float f32x4 __attribute__((ext_vector_type(4)));

#define AS1 __attribute__((address_space(1)))
#define AS3 __attribute__((address_space(3)))

__device__ __forceinline__ void async_lds16(const void* g, void* s) {
    __builtin_amdgcn_global_load_lds((const AS1 void*)g, (AS3 void*)s, 16, 0, 0);
}

// ---------------- weight transpose + cast: src (R x C) f32 -> dst (C x R) bf16
__global__ __launch_bounds__(256) void k_transpose_bf16(
    const float* __restrict__ src, bf16_t* __restrict__ dst, int R, int C) {
    __shared__ float tile[32][33];
    const int tx = threadIdx.x & 31, ty = threadIdx.x >> 5;
    const int r0 = blockIdx.y << 5, c0 = blockIdx.x << 5;
#pragma unroll
    for (int i = 0; i < 32; i += 8)
        tile[ty + i][tx] = src[(size_t)(r0 + ty + i) * C + c0 + tx];
    __syncthreads();
#pragma unroll
    for (int i = 0; i < 32; i += 8)
        dst[(size_t)(c0 + ty + i) * R + r0 + tx] = (bf16_t)tile[tx][ty + i];
}

// ---------------- layernorm: x (rows x 1024) f32 -> out bf16
__global__ __launch_bounds__(256) void k_layernorm(
    const float* __restrict__ x, const float* __restrict__ g,
    const float* __restrict__ b, bf16_t* __restrict__ out) {
    const int row = blockIdx.x;
    const int t = threadIdx.x;
    const float4 xv = reinterpret_cast<const float4*>(x + (size_t)row * 1024)[t];
    float s = xv.x + xv.y + xv.z + xv.w;
    float s2 = xv.x * xv.x + xv.y * xv.y + xv.z * xv.z + xv.w * xv.w;
#pragma unroll
    for (int mk = 32; mk >= 1; mk >>= 1) {
        s += __shfl_xor(s, mk);
        s2 += __shfl_xor(s2, mk);
    }
    __shared__ float red[8];
    const int w = t >> 6, l = t & 63;
    if (l == 0) { red[w] = s; red[4 + w] = s2; }
    __syncthreads();
    s = red[0] + red[1] + red[2] + red[3];
    s2 = red[4] + red[5] + red[6] + red[7];
    const float mu = s * (1.0f / 1024.0f);
    const float var = s2 * (1.0f / 1024.0f) - mu * mu;
    const float rs = rsqrtf(var + 1e-5f);
    const float4 gv = reinterpret_cast<const float4*>(g)[t];
    const float4 bv = reinterpret_cast<const float4*>(b)[t];
    bf16x4 o4;
    o4[0] = (bf16_t)((xv.x - mu) * rs * gv.x + bv.x);
    o4[1] = (bf16_t)((xv.y - mu) * rs * gv.y + bv.y);
    o4[2] = (bf16_t)((xv.z - mu) * rs * gv.z + bv.z);
    o4[3] = (bf16_t)((xv.w - mu) * rs * gv.w + bv.w);
    *reinterpret_cast<bf16x4*>(out + (size_t)row * 1024 + t * 4) = o4;
}

// ---------------- GEMM: C = A(MxK,bf16) * BT(NxK,bf16)^T + epilogue
enum { EPI_QKV = 0, EPI_RESID = 1, EPI_GELU = 2 };

template <int EPI>
__global__ __launch_bounds__(256, 2) void k_gemm(
    const bf16_t* __restrict__ A, const bf16_t* __restrict__ BT,
    const float* __restrict__ bias, const float* __restrict__ resid,
    float* __restrict__ outF, bf16_t* __restrict__ outB,
    int M, int N, int K, float scale) {
    const int mbase = blockIdx.y * 128;
    const int nbase = blockIdx.x * 128;
    const int t = threadIdx.x;
    const int w = t >> 6, l = t & 63;
    const int wr = w >> 1, wc = w & 1;
    const int lrow = l & 15, lk = (l >> 4) * 8;

    __shared__ alignas(16) bf16_t As[128 * 32];
    __shared__ alignas(16) bf16_t Bs[128 * 32];

    f32x4 acc[4][4] = {};

    const int sr = t >> 2;        // staging row 0..63
    const int sk = (t & 3) * 8;   // staging k element offset
    const size_t arow0 = (size_t)(mbase + sr) * K;
    const size_t arow1 = (size_t)(mbase + 64 + sr) * K;
    const size_t brow0 = (size_t)(nbase + sr) * K;
    const size_t brow1 = (size_t)(nbase + 64 + sr) * K;

    for (int k0 = 0; k0 < K; k0 += 32) {
        __syncthreads();
        async_lds16(A + arow0 + k0 + sk, As + t * 8);
        async_lds16(A + arow1 + k0 + sk, As + 2048 + t * 8);
        async_lds16(BT + brow0 + k0 + sk, Bs + t * 8);
        async_lds16(BT + brow1 + k0 + sk, Bs + 2048 + t * 8);
        __syncthreads();
        bf16x8 a[4], b[4];
#pragma unroll
        for (int i = 0; i < 4; i++)
            a[i] = *reinterpret_cast<const bf16x8*>(As + (wr * 64 + i * 16 + lrow) * 32 + lk);
#pragma unroll
        for (int j = 0; j < 4; j++)
            b[j] = *reinterpret_cast<const bf16x8*>(Bs + (wc * 64 + j * 16 + lrow) * 32 + lk);
#pragma unroll
        for (int i = 0; i < 4; i++)
#pragma unroll
            for (int j = 0; j < 4; j++)
                acc[i][j] = __builtin_amdgcn_mfma_f32_16x16x32_bf16(a[i], b[j], acc[i][j], 0, 0, 0);
    }

#pragma unroll
    for (int i = 0; i < 4; i++) {
#pragma unroll
        for (int j = 0; j < 4; j++) {
            const int col = nbase + wc * 64 + j * 16 + lrow;
            const float bj = bias[col];
#pragma unroll
            for (int r = 0; r < 4; r++) {
                const int row = mbase + wr * 64 + i * 16 + (l >> 4) * 4 + r;
                float v = acc[i][j][r] + bj;
                if constexpr (EPI == EPI_QKV) {
                    v *= scale;
                    const int bidx = row >> 10, ns = row & 1023;
                    const int hh = col >> 6, ch = col & 63;
                    outB[(((size_t)(bidx * 16 + hh)) * 1024 + ns) * 64 + ch] = (bf16_t)v;
                } else if constexpr (EPI == EPI_RESID) {
                    outF[(size_t)row * N + col] = v + resid[(size_t)row * N + col];
                } else {  // EPI_GELU, exact: 0.5*x*(1+erf(x/sqrt(2)))
                    const float ge = 0.5f * v * (1.0f + erff(v * 0.70710678118654752f));
                    outB[(size_t)row * N + col] = (bf16_t)ge;
                }
            }
        }
    }
}

// ---------------- flash attention, causal, 1 block per (bh, 64-row q tile)
__global__ __launch_bounds__(256, 2) void k_attn(
    const bf16_t* __restrict__ q, const bf16_t* __restrict__ kk,
    const bf16_t* __restrict__ vv, const unsigned char* __restrict__ pad,
    bf16_t* __restrict__ o) {
    const int qt = blockIdx.x;   // 0..15
    const int bh = blockIdx.y;   // 0..63
    const int bb = bh >> 4, hh = bh & 15;
    const int t = threadIdx.x;
    const int w = t >> 6, l = t & 63;
    const int lrow = l & 15, lg = l >> 4;
    const int qbase = qt * 64;

    __shared__ alignas(16) bf16_t Ks[64 * 64];
    __shared__ alignas(16) bf16_t Vt[64 * 64];
    __shared__ alignas(16) bf16_t Ps[4][16 * 64];

    const size_t bh_off = (size_t)bh * 1024 * 64;
    const int qrow = qbase + w * 16 + lrow;
    bf16x8 qf[2];
#pragma unroll
    for (int ks = 0; ks < 2; ks++)
        qf[ks] = *reinterpret_cast<const bf16x8*>(q + bh_off + (size_t)qrow * 64 + ks * 32 + lg * 8);

    f32x4 oacc[4] = {};
    float mrow[4] = {-1e30f, -1e30f, -1e30f, -1e30f};
    float lsum[4] = {0.f, 0.f, 0.f, 0.f};

    const int stg_r = t >> 3;         // 0..31
    const int stg_c = (t & 7) * 8;    // channel offset

    for (int kb = 0; kb < qbase + 64; kb += 64) {
        __syncthreads();
        const bf16_t* kp = kk + bh_off + (size_t)kb * 64;
        async_lds16(kp + (size_t)stg_r * 64 + stg_c, Ks + t * 8);
        async_lds16(kp + (size_t)(32 + stg_r) * 64 + stg_c, Ks + 2048 + t * 8);
        const bf16_t* vp = vv + bh_off + (size_t)kb * 64;
#pragma unroll
        for (int pass = 0; pass < 2; pass++) {
            const int kvi = pass * 32 + stg_r;
            bf16x8 vl = *reinterpret_cast<const bf16x8*>(vp + (size_t)kvi * 64 + stg_c);
#pragma unroll
            for (int e = 0; e < 8; e++)
                Vt[(stg_c + e) * 64 + kvi] = vl[e];
        }
        __syncthreads();

        // S = Q K^T (16 rows x 64 kv)
        f32x4 s[4] = {};
#pragma unroll
        for (int ks = 0; ks < 2; ks++) {
#pragma unroll
            for (int jt = 0; jt < 4; jt++) {
                bf16x8 bfr = *reinterpret_cast<const bf16x8*>(Ks + (jt * 16 + lrow) * 64 + ks * 32 + lg * 8);
                s[jt] = __builtin_amdgcn_mfma_f32_16x16x32_bf16(qf[ks], bfr, s[jt], 0, 0, 0);
            }
        }
        // causal + pad mask
#pragma unroll
        for (int jt = 0; jt < 4; jt++) {
            const int kvg = kb + jt * 16 + lrow;
            const bool padm = pad[bb * 1024 + kvg] != 0;
#pragma unroll
            for (int r = 0; r < 4; r++) {
                const int qg = qbase + w * 16 + lg * 4 + r;
                if (kvg > qg || padm) s[jt][r] = -1e30f;
            }
        }
        // online softmax (row groups of 16 lanes)
        float alpha[4];
#pragma unroll
        for (int r = 0; r < 4; r++) {
            float mx = fmaxf(fmaxf(s[0][r], s[1][r]), fmaxf(s[2][r], s[3][r]));
#pragma unroll
            for (int mk = 8; mk >= 1; mk >>= 1) mx = fmaxf(mx, __shfl_xor(mx, mk));
            const float mn = fmaxf(mrow[r], mx);
            alpha[r] = __expf(mrow[r] - mn);
            mrow[r] = mn;
        }
#pragma unroll
        for (int jt = 0; jt < 4; jt++)
#pragma unroll
            for (int r = 0; r < 4; r++)
                s[jt][r] = __expf(s[jt][r] - mrow[r]);
#pragma unroll
        for (int r = 0; r < 4; r++) {
            float sm = s[0][r] + s[1][r] + s[2][r] + s[3][r];
#pragma unroll
            for (int mk = 8; mk >= 1; mk >>= 1) sm += __shfl_xor(sm, mk);
            lsum[r] = lsum[r] * alpha[r] + sm;
        }
#pragma unroll
        for (int ct = 0; ct < 4; ct++)
#pragma unroll
            for (int r = 0; r < 4; r++)
                oacc[ct][r] *= alpha[r];
        // P -> LDS (per wave), convert to A-fragment layout
#pragma unroll
        for (int jt = 0; jt < 4; jt++)
#pragma unroll
            for (int r = 0; r < 4; r++)
                Ps[w][(lg * 4 + r) * 64 + jt * 16 + lrow] = (bf16_t)s[jt][r];
        // PV (same-wave LDS RAW: DS ops are in-order within a wave)
#pragma unroll
        for (int ks = 0; ks < 2; ks++) {
            bf16x8 pa = *reinterpret_cast<const bf16x8*>(&Ps[w][lrow * 64 + ks * 32 + lg * 8]);
#pragma unroll
            for (int ct = 0; ct < 4; ct++) {
                bf16x8 vb = *reinterpret_cast<const bf16x8*>(Vt + (ct * 16 + lrow) * 64 + ks * 32 + lg * 8);
                oacc[ct] = __builtin_amdgcn_mfma_f32_16x16x32_bf16(pa, vb, oacc[ct], 0, 0, 0);
            }
        }
    }
    // epilogue: o[b][n][h*64+ch] bf16
#pragma unroll
    for (int ct = 0; ct < 4; ct++) {
#pragma unroll
        for (int r = 0; r < 4; r++) {
            const int qg = qbase + w * 16 + lg * 4 + r;
            const float val = oacc[ct][r] / lsum[r];
            o[((size_t)bb * 1024 + qg) * 1024 + hh * 64 + ct * 16 + lrow] = (bf16_t)val;
        }
    }
}

extern "C" void kernel_launch(void* const* d_in, const int* in_sizes, int n_in,
                              void* d_out, int out_size, void* d_ws, size_t ws_size,
                              hipStream_t stream) {
    const float* x    = (const float*)d_in[0];
    const float* ln1g = (const float*)d_in[1];
    const float* ln1b = (const float*)d_in[2];
    const float* Wq   = (const float*)d_in[3];
    const float* bq   = (const float*)d_in[4];
    const float* Wk   = (const float*)d_in[5];
    const float* bk   = (const float*)d_in[6];
    const float* Wv   = (const float*)d_in[7];
    const float* bv   = (const float*)d_in[8];
    const float* Wo   = (const float*)d_in[9];
    const float* bo   = (const float*)d_in[10];
    const float* ln2g = (const float*)d_in[11];
    const float* ln2b = (const float*)d_in[12];
    const float* W1   = (const float*)d_in[13];
    const float* b1   = (const float*)d_in[14];
    const float* W2   = (const float*)d_in[15];
    const float* b2   = (const float*)d_in[16];
    const unsigned char* pad = (const unsigned char*)d_in[17];

    char* ws = (char*)d_ws;
    const size_t MB = 1024 * 1024;
    bf16_t* WqT = (bf16_t*)(ws + 0 * MB);
    bf16_t* WkT = (bf16_t*)(ws + 2 * MB);
    bf16_t* WvT = (bf16_t*)(ws + 4 * MB);
    bf16_t* WoT = (bf16_t*)(ws + 6 * MB);
    bf16_t* W1T = (bf16_t*)(ws + 8 * MB);
    bf16_t* W2T = (bf16_t*)(ws + 16 * MB);
    bf16_t* h   = (bf16_t*)(ws + 24 * MB);
    bf16_t* qb  = (bf16_t*)(ws + 32 * MB);
    bf16_t* kb  = (bf16_t*)(ws + 40 * MB);
    bf16_t* vb  = (bf16_t*)(ws + 48 * MB);
    bf16_t* hid = (bf16_t*)(ws + 24 * MB);  // overlays h,q,k,v (dead by then)
    bf16_t* ob  = (bf16_t*)(ws + 56 * MB);
    bf16_t* m2  = (bf16_t*)(ws + 56 * MB);  // overlays ob (dead by then)
    float*  x2  = (float*)(ws + 64 * MB);   // 16MB; total 80MB

    const dim3 blk(256);
    // weight transposes (f32 -> bf16, W^T)
    k_transpose_bf16<<<dim3(32, 32), blk, 0, stream>>>(Wq, WqT, 1024, 1024);
    k_transpose_bf16<<<dim3(32, 32), blk, 0, stream>>>(Wk, WkT, 1024, 1024);
    k_transpose_bf16<<<dim3(32, 32), blk, 0, stream>>>(Wv, WvT, 1024, 1024);
    k_transpose_bf16<<<dim3(32, 32), blk, 0, stream>>>(Wo, WoT, 1024, 1024);
    k_transpose_bf16<<<dim3(128, 32), blk, 0, stream>>>(W1, W1T, 1024, 4096);
    k_transpose_bf16<<<dim3(32, 128), blk, 0, stream>>>(W2, W2T, 4096, 1024);
    // LN1
    k_layernorm<<<4096, blk, 0, stream>>>(x, ln1g, ln1b, h);
    // QKV projections (q scaled by c^-0.5 = 0.125)
    k_gemm<EPI_QKV><<<dim3(8, 32), blk, 0, stream>>>(h, WqT, bq, nullptr, nullptr, qb, 4096, 1024, 1024, 0.125f);
    k_gemm<EPI_QKV><<<dim3(8, 32), blk, 0, stream>>>(h, WkT, bk, nullptr, nullptr, kb, 4096, 1024, 1024, 1.0f);
    k_gemm<EPI_QKV><<<dim3(8, 32), blk, 0, stream>>>(h, WvT, bv, nullptr, nullptr, vb, 4096, 1024, 1024, 1.0f);
    // attention
    k_attn<<<dim3(16, 64), blk, 0, stream>>>(qb, kb, vb, pad, ob);
    // O projection + residual -> x2 (f32)
    k_gemm<EPI_RESID><<<dim3(8, 32), blk, 0, stream>>>(ob, WoT, bo, x, x2, nullptr, 4096, 1024, 1024, 1.0f);
    // LN2
    k_layernorm<<<4096, blk, 0, stream>>>(x2, ln2g, ln2b, m2);
    // MLP
    k_gemm<EPI_GELU><<<dim3(32, 32), blk, 0, stream>>>(m2, W1T, b1, nullptr, nullptr, hid, 4096, 4096, 1024, 1.0f);
    k_gemm<EPI_RESID><<<dim3(8, 32), blk, 0, stream>>>(hid, W2T, b2, x2, (float*)d_out, nullptr, 4096, 1024, 4096, 1.0f);
}

// Round 2
// 292.475 us; speedup vs baseline: 1.2788x; 1.2788x over previous
//
#include <hip/hip_runtime.h>
#include <hip/hip_bf16.h>
#include <cmath>

typedef __bf16 bf16_t;
typedef __bf16 bf16x8 __attribute__((ext_vector_type(8)));
typedef __bf16 bf16x4 __attribute__((ext_vector_type(4)));
typedef float f32x4 __attribute__((ext_vector_type(4)));

#define AS1 __attribute__((address_space(1)))
#define AS3 __attribute__((address_space(3)))

__device__ __forceinline__ void async_lds16(const void* g, void* s) {
    __builtin_amdgcn_global_load_lds((const AS1 void*)g, (AS3 void*)s, 16, 0, 0);
}

// ---------------- weight transpose + cast: src (R x C) f32 -> dst (C x R) bf16
__global__ __launch_bounds__(256) void k_transpose_bf16(
    const float* __restrict__ src, bf16_t* __restrict__ dst, int R, int C) {
    __shared__ float tile[32][33];
    const int tx = threadIdx.x & 31, ty = threadIdx.x >> 5;
    const int r0 = blockIdx.y << 5, c0 = blockIdx.x << 5;
#pragma unroll
    for (int i = 0; i < 32; i += 8)
        tile[ty + i][tx] = src[(size_t)(r0 + ty + i) * C + c0 + tx];
    __syncthreads();
#pragma unroll
    for (int i = 0; i < 32; i += 8)
        dst[(size_t)(c0 + ty + i) * R + r0 + tx] = (bf16_t)tile[tx][ty + i];
}

// ---------------- layernorm: x (rows x 1024) f32 -> out bf16
__global__ __launch_bounds__(256) void k_layernorm(
    const float* __restrict__ x, const float* __restrict__ g,
    const float* __restrict__ b, bf16_t* __restrict__ out) {
    const int row = blockIdx.x;
    const int t = threadIdx.x;
    const float4 xv = reinterpret_cast<const float4*>(x + (size_t)row * 1024)[t];
    float s = xv.x + xv.y + xv.z + xv.w;
    float s2 = xv.x * xv.x + xv.y * xv.y + xv.z * xv.z + xv.w * xv.w;
#pragma unroll
    for (int mk = 32; mk >= 1; mk >>= 1) {
        s += __shfl_xor(s, mk);
        s2 += __shfl_xor(s2, mk);
    }
    __shared__ float red[8];
    const int w = t >> 6, l = t & 63;
    if (l == 0) { red[w] = s; red[4 + w] = s2; }
    __syncthreads();
    s = red[0] + red[1] + red[2] + red[3];
    s2 = red[4] + red[5] + red[6] + red[7];
    const float mu = s * (1.0f / 1024.0f);
    const float var = s2 * (1.0f / 1024.0f) - mu * mu;
    const float rs = rsqrtf(var + 1e-5f);
    const float4 gv = reinterpret_cast<const float4*>(g)[t];
    const float4 bv = reinterpret_cast<const float4*>(b)[t];
    bf16x4 o4;
    o4[0] = (bf16_t)((xv.x - mu) * rs * gv.x + bv.x);
    o4[1] = (bf16_t)((xv.y - mu) * rs * gv.y + bv.y);
    o4[2] = (bf16_t)((xv.z - mu) * rs * gv.z + bv.z);
    o4[3] = (bf16_t)((xv.w - mu) * rs * gv.w + bv.w);
    *reinterpret_cast<bf16x4*>(out + (size_t)row * 1024 + t * 4) = o4;
}

// ---------------- GEMM: C = A(MxK,bf16) * BT(NxK,bf16)^T + epilogue
// LDS tiles [128 rows][32 bf16] with 16B-chunk XOR swizzle: chunk' = chunk ^ (row&3)
enum { EPI_QKV = 0, EPI_RESID = 1, EPI_GELU = 2 };

template <int EPI>
__global__ __launch_bounds__(256, 2) void k_gemm(
    const bf16_t* __restrict__ A, const bf16_t* __restrict__ BT,
    const float* __restrict__ bias0, const float* __restrict__ bias1,
    const float* __restrict__ bias2, const float* __restrict__ resid,
    float* __restrict__ outF, bf16_t* __restrict__ outB,
    bf16_t* __restrict__ outB2, bf16_t* __restrict__ outB3,
    int M, int N, int K) {
    const int mbase = blockIdx.y * 128;
    const int nbase = blockIdx.x * 128;
    const int t = threadIdx.x;
    const int w = t >> 6, l = t & 63;
    const int wr = w >> 1, wc = w & 1;
    const int lrow = l & 15, lg = l >> 4;

    __shared__ alignas(16) bf16_t As[128 * 32];
    __shared__ alignas(16) bf16_t Bs[128 * 32];

    f32x4 acc[4][4] = {};

    const int sr = t >> 2;                  // staging row 0..63
    const int sc = t & 3;                   // staging 16B-chunk 0..3
    const int ssw = (sc ^ (sr & 3)) * 8;    // swizzled source element offset
    const size_t arow0 = (size_t)(mbase + sr) * K;
    const size_t arow1 = (size_t)(mbase + 64 + sr) * K;
    const size_t brow0 = (size_t)(nbase + sr) * K;
    const size_t brow1 = (size_t)(nbase + 64 + sr) * K;

    for (int k0 = 0; k0 < K; k0 += 32) {
        __syncthreads();
        async_lds16(A + arow0 + k0 + ssw, As + t * 8);
        async_lds16(A + arow1 + k0 + ssw, As + 2048 + t * 8);
        async_lds16(BT + brow0 + k0 + ssw, Bs + t * 8);
        async_lds16(BT + brow1 + k0 + ssw, Bs + 2048 + t * 8);
        __syncthreads();
        bf16x8 a[4], b[4];
#pragma unroll
        for (int i = 0; i < 4; i++) {
            const int r = wr * 64 + i * 16 + lrow;
            a[i] = *reinterpret_cast<const bf16x8*>(As + r * 32 + ((lg ^ (r & 3)) * 8));
        }
#pragma unroll
        for (int j = 0; j < 4; j++) {
            const int r = wc * 64 + j * 16 + lrow;
            b[j] = *reinterpret_cast<const bf16x8*>(Bs + r * 32 + ((lg ^ (r & 3)) * 8));
        }
#pragma unroll
        for (int i = 0; i < 4; i++)
#pragma unroll
            for (int j = 0; j < 4; j++)
                acc[i][j] = __builtin_amdgcn_mfma_f32_16x16x32_bf16(a[i], b[j], acc[i][j], 0, 0, 0);
    }

#pragma unroll
    for (int i = 0; i < 4; i++) {
#pragma unroll
        for (int j = 0; j < 4; j++) {
            const int col = nbase + wc * 64 + j * 16 + lrow;
            float bj;
            int kind = 0, cc = col;
            if constexpr (EPI == EPI_QKV) {
                kind = col >> 10; cc = col & 1023;
                bj = (kind == 0 ? bias0 : kind == 1 ? bias1 : bias2)[cc];
            } else {
                bj = bias0[col];
            }
#pragma unroll
            for (int r = 0; r < 4; r++) {
                const int row = mbase + wr * 64 + i * 16 + (l >> 4) * 4 + r;
                float v = acc[i][j][r] + bj;
                if constexpr (EPI == EPI_QKV) {
                    const int bidx = row >> 10, ns = row & 1023;
                    const int hh = cc >> 6, ch = cc & 63;
                    const int bhh = bidx * 16 + hh;
                    if (kind == 0)
                        outB[((size_t)bhh * 1024 + ns) * 64 + ch] = (bf16_t)(v * 0.125f);
                    else if (kind == 1)
                        outB2[((size_t)bhh * 1024 + ns) * 64 + ch] = (bf16_t)v;
                    else  // V stored transposed: [bh][ch][n]
                        outB3[((size_t)bhh * 64 + ch) * 1024 + ns] = (bf16_t)v;
                } else if constexpr (EPI == EPI_RESID) {
                    outF[(size_t)row * N + col] = v + resid[(size_t)row * N + col];
                } else {  // EPI_GELU, exact: 0.5*x*(1+erf(x/sqrt(2)))
                    const float ge = 0.5f * v * (1.0f + erff(v * 0.70710678118654752f));
                    outB[(size_t)row * N + col] = (bf16_t)ge;
                }
            }
        }
    }
}

// ---------------- flash attention, causal, 1 block per (bh, 64-row q tile)
// K tile [64 kv][64 ch], V^T tile [64 ch][64 kv], P tile [16 q][64 kv]:
// all rows = 8 x 16B chunks, XOR-swizzled chunk' = chunk ^ (row&7).
__global__ __launch_bounds__(256, 2) void k_attn(
    const bf16_t* __restrict__ q, const bf16_t* __restrict__ kk,
    const bf16_t* __restrict__ vt, const unsigned char* __restrict__ pad,
    bf16_t* __restrict__ o) {
    const int qt = blockIdx.x;   // 0..15
    const int bh = blockIdx.y;   // 0..63
    const int bb = bh >> 4, hh = bh & 15;
    const int t = threadIdx.x;
    const int w = t >> 6, l = t & 63;
    const int lrow = l & 15, lg = l >> 4;
    const int qbase = qt * 64;

    __shared__ alignas(16) bf16_t Ks[64 * 64];
    __shared__ alignas(16) bf16_t Vs[64 * 64];
    __shared__ alignas(16) bf16_t Ps[4][16 * 64];

    const size_t bh_off = (size_t)bh * 1024 * 64;
    const int qrow = qbase + w * 16 + lrow;
    bf16x8 qf[2];
#pragma unroll
    for (int ks = 0; ks < 2; ks++)
        qf[ks] = *reinterpret_cast<const bf16x8*>(q + bh_off + (size_t)qrow * 64 + ks * 32 + lg * 8);

    f32x4 oacc[4] = {};
    float mrow[4] = {-1e30f, -1e30f, -1e30f, -1e30f};
    float lsum[4] = {0.f, 0.f, 0.f, 0.f};

    const int sr = t >> 3;                // staging row 0..31
    const int ssw = ((t & 7) ^ (sr & 7)) * 8;  // swizzled source chunk offset

    for (int kb = 0; kb < qbase + 64; kb += 64) {
        __syncthreads();
        const bf16_t* kp = kk + bh_off + (size_t)kb * 64;
        async_lds16(kp + (size_t)sr * 64 + ssw, Ks + t * 8);
        async_lds16(kp + (size_t)(32 + sr) * 64 + ssw, Ks + 2048 + t * 8);
        const bf16_t* vp = vt + bh_off + kb;  // rows = channel, stride 1024
        async_lds16(vp + (size_t)sr * 1024 + ssw, Vs + t * 8);
        async_lds16(vp + (size_t)(32 + sr) * 1024 + ssw, Vs + 2048 + t * 8);
        __syncthreads();

        // S = Q K^T (16 q rows x 64 kv per wave)
        f32x4 s[4] = {};
#pragma unroll
        for (int ks = 0; ks < 2; ks++) {
#pragma unroll
            for (int jt = 0; jt < 4; jt++) {
                const int kr = jt * 16 + lrow;
                bf16x8 bfr = *reinterpret_cast<const bf16x8*>(
                    Ks + kr * 64 + (((ks * 4 + lg) ^ (kr & 7)) * 8));
                s[jt] = __builtin_amdgcn_mfma_f32_16x16x32_bf16(qf[ks], bfr, s[jt], 0, 0, 0);
            }
        }
        // causal + pad mask
#pragma unroll
        for (int jt = 0; jt < 4; jt++) {
            const int kvg = kb + jt * 16 + lrow;
            const bool padm = pad[bb * 1024 + kvg] != 0;
#pragma unroll
            for (int r = 0; r < 4; r++) {
                const int qg = qbase + w * 16 + lg * 4 + r;
                if (kvg > qg || padm) s[jt][r] = -1e30f;
            }
        }
        // online softmax (row groups of 16 lanes)
        float alpha[4];
#pragma unroll
        for (int r = 0; r < 4; r++) {
            float mx = fmaxf(fmaxf(s[0][r], s[1][r]), fmaxf(s[2][r], s[3][r]));
#pragma unroll
            for (int mk = 8; mk >= 1; mk >>= 1) mx = fmaxf(mx, __shfl_xor(mx, mk));
            const float mn = fmaxf(mrow[r], mx);
            alpha[r] = __expf(mrow[r] - mn);
            mrow[r] = mn;
        }
#pragma unroll
        for (int jt = 0; jt < 4; jt++)
#pragma unroll
            for (int r = 0; r < 4; r++)
                s[jt][r] = __expf(s[jt][r] - mrow[r]);
#pragma unroll
        for (int r = 0; r < 4; r++) {
            float sm = s[0][r] + s[1][r] + s[2][r] + s[3][r];
#pragma unroll
            for (int mk = 8; mk >= 1; mk >>= 1) sm += __shfl_xor(sm, mk);
            lsum[r] = lsum[r] * alpha[r] + sm;
        }
#pragma unroll
        for (int ct = 0; ct < 4; ct++)
#pragma unroll
            for (int r = 0; r < 4; r++)
                oacc[ct][r] *= alpha[r];
        // P -> LDS (per wave), swizzled, convert to A-fragment layout
#pragma unroll
        for (int jt = 0; jt < 4; jt++)
#pragma unroll
            for (int r = 0; r < 4; r++) {
                const int prow = lg * 4 + r;
                const int kvc = jt * 16 + lrow;
                Ps[w][prow * 64 + (((kvc >> 3) ^ (prow & 7)) * 8) + (kvc & 7)] = (bf16_t)s[jt][r];
            }
        // PV (same-wave LDS RAW; compiler orders DS ops within a wave)
#pragma unroll
        for (int ks = 0; ks < 2; ks++) {
            bf16x8 pa = *reinterpret_cast<const bf16x8*>(
                &Ps[w][lrow * 64 + (((ks * 4 + lg) ^ (lrow & 7)) * 8)]);
#pragma unroll
            for (int ct = 0; ct < 4; ct++) {
                const int vr = ct * 16 + lrow;
                bf16x8 vb = *reinterpret_cast<const bf16x8*>(
                    Vs + vr * 64 + (((ks * 4 + lg) ^ (vr & 7)) * 8));
                oacc[ct] = __builtin_amdgcn_mfma_f32_16x16x32_bf16(pa, vb, oacc[ct], 0, 0, 0);
            }
        }
    }
    // epilogue: o[b][n][h*64+ch] bf16
#pragma unroll
    for (int ct = 0; ct < 4; ct++) {
#pragma unroll
        for (int r = 0; r < 4; r++) {
            const int qg = qbase + w * 16 + lg * 4 + r;
            const float val = oacc[ct][r] / lsum[r];
            o[((size_t)bb * 1024 + qg) * 1024 + hh * 64 + ct * 16 + lrow] = (bf16_t)val;
        }
    }
}

extern "C" void kernel_launch(void* const* d_in, const int* in_sizes, int n_in,
                              void* d_out, int out_size, void* d_ws, size_t ws_size,
                              hipStream_t stream) {
    const float* x    = (const float*)d_in[0];
    const float* ln1g = (const float*)d_in[1];
    const float* ln1b = (const float*)d_in[2];
    const float* Wq   = (const float*)d_in[3];
    const float* bq   = (const float*)d_in[4];
    const float* Wk   = (const float*)d_in[5];
    const float* bk   = (const float*)d_in[6];
    const float* Wv   = (const float*)d_in[7];
    const float* bv   = (const float*)d_in[8];
    const float* Wo   = (const float*)d_in[9];
    const float* bo   = (const float*)d_in[10];
    const float* ln2g = (const float*)d_in[11];
    const float* ln2b = (const float*)d_in[12];
    const float* W1   = (const float*)d_in[13];
    const float* b1   = (const float*)d_in[14];
    const float* W2   = (const float*)d_in[15];
    const float* b2   = (const float*)d_in[16];
    const unsigned char* pad = (const unsigned char*)d_in[17];

    char* ws = (char*)d_ws;
    const size_t MB = 1024 * 1024;
    bf16_t* WqkvT = (bf16_t*)(ws + 0 * MB);   // 3072x1024 bf16 = 6MB
    bf16_t* WoT = (bf16_t*)(ws + 6 * MB);     // 2MB
    bf16_t* W1T = (bf16_t*)(ws + 8 * MB);     // 8MB
    bf16_t* W2T = (bf16_t*)(ws + 16 * MB);    // 8MB
    bf16_t* h   = (bf16_t*)(ws + 24 * MB);    // 8MB
    bf16_t* qb  = (bf16_t*)(ws + 32 * MB);    // 8MB
    bf16_t* kb  = (bf16_t*)(ws + 40 * MB);    // 8MB
    bf16_t* vb  = (bf16_t*)(ws + 48 * MB);    // 8MB (transposed [bh][ch][n])
    bf16_t* hid = (bf16_t*)(ws + 24 * MB);    // 32MB, overlays h,q,k,v (dead by then)
    bf16_t* ob  = (bf16_t*)(ws + 56 * MB);    // 8MB
    bf16_t* m2  = (bf16_t*)(ws + 56 * MB);    // overlays ob (dead by then)
    float*  x2  = (float*)(ws + 64 * MB);     // 16MB; total 80MB

    const dim3 blk(256);
    // weight transposes (f32 -> bf16, W^T); q/k/v packed into one 3072-row BT
    k_transpose_bf16<<<dim3(32, 32), blk, 0, stream>>>(Wq, WqkvT, 1024, 1024);
    k_transpose_bf16<<<dim3(32, 32), blk, 0, stream>>>(Wk, WqkvT + 1024 * 1024, 1024, 1024);
    k_transpose_bf16<<<dim3(32, 32), blk, 0, stream>>>(Wv, WqkvT + 2048 * 1024, 1024, 1024);
    k_transpose_bf16<<<dim3(32, 32), blk, 0, stream>>>(Wo, WoT, 1024, 1024);
    k_transpose_bf16<<<dim3(128, 32), blk, 0, stream>>>(W1, W1T, 1024, 4096);
    k_transpose_bf16<<<dim3(32, 128), blk, 0, stream>>>(W2, W2T, 4096, 1024);
    // LN1
    k_layernorm<<<4096, blk, 0, stream>>>(x, ln1g, ln1b, h);
    // fused QKV projection (q scaled by 0.125 in epilogue; V written transposed)
    k_gemm<EPI_QKV><<<dim3(24, 32), blk, 0, stream>>>(
        h, WqkvT, bq, bk, bv, nullptr, nullptr, qb, kb, vb, 4096, 3072, 1024);
    // attention
    k_attn<<<dim3(16, 64), blk, 0, stream>>>(qb, kb, vb, pad, ob);
    // O projection + residual -> x2 (f32)
    k_gemm<EPI_RESID><<<dim3(8, 32), blk, 0, stream>>>(
        ob, WoT, bo, nullptr, nullptr, x, x2, nullptr, nullptr, nullptr, 4096, 1024, 1024);
    // LN2
    k_layernorm<<<4096, blk, 0, stream>>>(x2, ln2g, ln2b, m2);
    // MLP
    k_gemm<EPI_GELU><<<dim3(32, 32), blk, 0, stream>>>(
        m2, W1T, b1, nullptr, nullptr, nullptr, nullptr, hid, nullptr, nullptr, 4096, 4096, 1024);
    k_gemm<EPI_RESID><<<dim3(8, 32), blk, 0, stream>>>(
        hid, W2T, b2, nullptr, nullptr, x2, (float*)d_out, nullptr, nullptr, nullptr, 4096, 1024, 4096);
}

// Round 3
// 278.415 us; speedup vs baseline: 1.3434x; 1.0505x over previous
//
#include <hip/hip_runtime.h>
#include <hip/hip_bf16.h>
#include <cmath>

typedef __bf16 bf16_t;
typedef __bf16 bf16x8 __attribute__((ext_vector_type(8)));
typedef __bf16 bf16x4 __attribute__((ext_vector_type(4)));
typedef float f32x4 __attribute__((ext_vector_type(4)));

#define AS1 __attribute__((address_space(1)))
#define AS3 __attribute__((address_space(3)))

__device__ __forceinline__ void async_lds16(const void* g, void* s) {
    __builtin_amdgcn_global_load_lds((const AS1 void*)g, (AS3 void*)s, 16, 0, 0);
}

// ---------------- weight transpose + cast: src (R x C) f32 -> dst (C x R) bf16
__global__ __launch_bounds__(256) void k_transpose_bf16(
    const float* __restrict__ src, bf16_t* __restrict__ dst, int R, int C) {
    __shared__ float tile[32][33];
    const int tx = threadIdx.x & 31, ty = threadIdx.x >> 5;
    const int r0 = blockIdx.y << 5, c0 = blockIdx.x << 5;
#pragma unroll
    for (int i = 0; i < 32; i += 8)
        tile[ty + i][tx] = src[(size_t)(r0 + ty + i) * C + c0 + tx];
    __syncthreads();
#pragma unroll
    for (int i = 0; i < 32; i += 8)
        dst[(size_t)(c0 + ty + i) * R + r0 + tx] = (bf16_t)tile[tx][ty + i];
}

// ---------------- layernorm: x (rows x 1024) f32 -> out bf16
__global__ __launch_bounds__(256) void k_layernorm(
    const float* __restrict__ x, const float* __restrict__ g,
    const float* __restrict__ b, bf16_t* __restrict__ out) {
    const int row = blockIdx.x;
    const int t = threadIdx.x;
    const float4 xv = reinterpret_cast<const float4*>(x + (size_t)row * 1024)[t];
    float s = xv.x + xv.y + xv.z + xv.w;
    float s2 = xv.x * xv.x + xv.y * xv.y + xv.z * xv.z + xv.w * xv.w;
#pragma unroll
    for (int mk = 32; mk >= 1; mk >>= 1) {
        s += __shfl_xor(s, mk);
        s2 += __shfl_xor(s2, mk);
    }
    __shared__ float red[8];
    const int w = t >> 6, l = t & 63;
    if (l == 0) { red[w] = s; red[4 + w] = s2; }
    __syncthreads();
    s = red[0] + red[1] + red[2] + red[3];
    s2 = red[4] + red[5] + red[6] + red[7];
    const float mu = s * (1.0f / 1024.0f);
    const float var = s2 * (1.0f / 1024.0f) - mu * mu;
    const float rs = rsqrtf(var + 1e-5f);
    const float4 gv = reinterpret_cast<const float4*>(g)[t];
    const float4 bv = reinterpret_cast<const float4*>(b)[t];
    bf16x4 o4;
    o4[0] = (bf16_t)((xv.x - mu) * rs * gv.x + bv.x);
    o4[1] = (bf16_t)((xv.y - mu) * rs * gv.y + bv.y);
    o4[2] = (bf16_t)((xv.z - mu) * rs * gv.z + bv.z);
    o4[3] = (bf16_t)((xv.w - mu) * rs * gv.w + bv.w);
    *reinterpret_cast<bf16x4*>(out + (size_t)row * 1024 + t * 4) = o4;
}

// ---------------- GEMM: C = A(MxK,bf16) * BT(NxK,bf16)^T + epilogue
// Double-buffered LDS, ONE __syncthreads per K-step (stage t+1 issued before
// compute of t). LDS rows 32 bf16 (64B), 16B-chunk swizzle chunk^=((row>>1)&3)
// -> 2-way (free) bank aliasing on ds_read_b128.
enum { EPI_QKV = 0, EPI_RESID = 1, EPI_GELU = 2 };

template <int EPI, int BM, int BN>
__global__ __launch_bounds__(256) void k_gemm(
    const bf16_t* __restrict__ A, const bf16_t* __restrict__ BT,
    const float* __restrict__ bias0, const float* __restrict__ bias1,
    const float* __restrict__ bias2, const float* __restrict__ resid,
    float* __restrict__ outF, bf16_t* __restrict__ outB,
    bf16_t* __restrict__ outB2, bf16_t* __restrict__ outB3,
    int M, int N, int K) {
    constexpr int WM = BM / 2, WN = BN / 2;
    constexpr int FI = WM / 16, FJ = WN / 16;

    // XCD-aware bijective swizzle (all grids here are %8==0; guarded anyway)
    const int gx = gridDim.x;
    const int nwg = gx * gridDim.y;
    int lin = blockIdx.y * gx + blockIdx.x;
    if ((nwg & 7) == 0) lin = (lin & 7) * (nwg >> 3) + (lin >> 3);
    const int mbase = (lin / gx) * BM;
    const int nbase = (lin % gx) * BN;

    const int t = threadIdx.x;
    const int w = t >> 6, l = t & 63;
    const int wr = w >> 1, wc = w & 1;
    const int lrow = l & 15, lg = l >> 4;

    __shared__ alignas(16) bf16_t As[2][BM * 32];
    __shared__ alignas(16) bf16_t Bs[2][BN * 32];

    f32x4 acc[FI][FJ] = {};

    const int sr = t >> 2;                        // staging row 0..63
    const int sc = t & 3;                         // staging 16B chunk
    const int ssw = (sc ^ ((sr >> 1) & 3)) * 8;   // swizzled source offset

    auto stage = [&](int k0, int buf) {
#pragma unroll
        for (int c = 0; c < BM / 64; c++)
            async_lds16(A + (size_t)(mbase + c * 64 + sr) * K + k0 + ssw,
                        As[buf] + c * 2048 + t * 8);
#pragma unroll
        for (int c = 0; c < BN / 64; c++)
            async_lds16(BT + (size_t)(nbase + c * 64 + sr) * K + k0 + ssw,
                        Bs[buf] + c * 2048 + t * 8);
    };

    stage(0, 0);
    const int nt = K >> 5;
    for (int tt = 0; tt < nt; tt++) {
        const int cur = tt & 1;
        __syncthreads();                 // drain stage(tt) + buffer-reuse barrier
        if (tt + 1 < nt) stage((tt + 1) << 5, cur ^ 1);
        bf16x8 a[FI], b[FJ];
#pragma unroll
        for (int i = 0; i < FI; i++) {
            const int r = wr * WM + i * 16 + lrow;
            a[i] = *reinterpret_cast<const bf16x8*>(
                As[cur] + r * 32 + ((lg ^ ((r >> 1) & 3)) * 8));
        }
#pragma unroll
        for (int j = 0; j < FJ; j++) {
            const int r = wc * WN + j * 16 + lrow;
            b[j] = *reinterpret_cast<const bf16x8*>(
                Bs[cur] + r * 32 + ((lg ^ ((r >> 1) & 3)) * 8));
        }
#pragma unroll
        for (int i = 0; i < FI; i++)
#pragma unroll
            for (int j = 0; j < FJ; j++)
                acc[i][j] = __builtin_amdgcn_mfma_f32_16x16x32_bf16(a[i], b[j], acc[i][j], 0, 0, 0);
    }

#pragma unroll
    for (int i = 0; i < FI; i++) {
#pragma unroll
        for (int j = 0; j < FJ; j++) {
            const int col = nbase + wc * WN + j * 16 + lrow;
            float bj;
            int kind = 0, cc = col;
            if constexpr (EPI == EPI_QKV) {
                kind = col >> 10; cc = col & 1023;
                bj = (kind == 0 ? bias0 : kind == 1 ? bias1 : bias2)[cc];
            } else {
                bj = bias0[col];
            }
#pragma unroll
            for (int r = 0; r < 4; r++) {
                const int row = mbase + wr * WM + i * 16 + lg * 4 + r;
                float v = acc[i][j][r] + bj;
                if constexpr (EPI == EPI_QKV) {
                    const int bidx = row >> 10, ns = row & 1023;
                    const int hh = cc >> 6, ch = cc & 63;
                    const int bhh = bidx * 16 + hh;
                    if (kind == 0)
                        outB[((size_t)bhh * 1024 + ns) * 64 + ch] = (bf16_t)(v * 0.125f);
                    else if (kind == 1)
                        outB2[((size_t)bhh * 1024 + ns) * 64 + ch] = (bf16_t)v;
                    else  // V stored transposed: [bh][ch][n]
                        outB3[((size_t)bhh * 64 + ch) * 1024 + ns] = (bf16_t)v;
                } else if constexpr (EPI == EPI_RESID) {
                    outF[(size_t)row * N + col] = v + resid[(size_t)row * N + col];
                } else {  // EPI_GELU, exact: 0.5*x*(1+erf(x/sqrt(2)))
                    const float ge = 0.5f * v * (1.0f + erff(v * 0.70710678118654752f));
                    outB[(size_t)row * N + col] = (bf16_t)ge;
                }
            }
        }
    }
}

// ---------------- flash attention, causal, 1 block per (bh, 64-row q tile)
// K tile [64 kv][64 ch], V^T tile [64 ch][64 kv], P tile [16 q][64 kv]:
// all rows = 8 x 16B chunks, XOR-swizzled chunk' = chunk ^ (row&7).
__global__ __launch_bounds__(256, 2) void k_attn(
    const bf16_t* __restrict__ q, const bf16_t* __restrict__ kk,
    const bf16_t* __restrict__ vt, const unsigned char* __restrict__ pad,
    bf16_t* __restrict__ o) {
    const int qt = blockIdx.x;   // 0..15
    const int bh = blockIdx.y;   // 0..63
    const int bb = bh >> 4, hh = bh & 15;
    const int t = threadIdx.x;
    const int w = t >> 6, l = t & 63;
    const int lrow = l & 15, lg = l >> 4;
    const int qbase = qt * 64;

    __shared__ alignas(16) bf16_t Ks[64 * 64];
    __shared__ alignas(16) bf16_t Vs[64 * 64];
    __shared__ alignas(16) bf16_t Ps[4][16 * 64];

    const size_t bh_off = (size_t)bh * 1024 * 64;
    const int qrow = qbase + w * 16 + lrow;
    bf16x8 qf[2];
#pragma unroll
    for (int ks = 0; ks < 2; ks++)
        qf[ks] = *reinterpret_cast<const bf16x8*>(q + bh_off + (size_t)qrow * 64 + ks * 32 + lg * 8);

    f32x4 oacc[4] = {};
    float mrow[4] = {-1e30f, -1e30f, -1e30f, -1e30f};
    float lsum[4] = {0.f, 0.f, 0.f, 0.f};

    const int sr = t >> 3;                // staging row 0..31
    const int ssw = ((t & 7) ^ (sr & 7)) * 8;  // swizzled source chunk offset

    for (int kb = 0; kb < qbase + 64; kb += 64) {
        __syncthreads();
        const bf16_t* kp = kk + bh_off + (size_t)kb * 64;
        async_lds16(kp + (size_t)sr * 64 + ssw, Ks + t * 8);
        async_lds16(kp + (size_t)(32 + sr) * 64 + ssw, Ks + 2048 + t * 8);
        const bf16_t* vp = vt + bh_off + kb;  // rows = channel, stride 1024
        async_lds16(vp + (size_t)sr * 1024 + ssw, Vs + t * 8);
        async_lds16(vp + (size_t)(32 + sr) * 1024 + ssw, Vs + 2048 + t * 8);
        __syncthreads();

        // S = Q K^T (16 q rows x 64 kv per wave)
        f32x4 s[4] = {};
#pragma unroll
        for (int ks = 0; ks < 2; ks++) {
#pragma unroll
            for (int jt = 0; jt < 4; jt++) {
                const int kr = jt * 16 + lrow;
                bf16x8 bfr = *reinterpret_cast<const bf16x8*>(
                    Ks + kr * 64 + (((ks * 4 + lg) ^ (kr & 7)) * 8));
                s[jt] = __builtin_amdgcn_mfma_f32_16x16x32_bf16(qf[ks], bfr, s[jt], 0, 0, 0);
            }
        }
        // causal + pad mask
#pragma unroll
        for (int jt = 0; jt < 4; jt++) {
            const int kvg = kb + jt * 16 + lrow;
            const bool padm = pad[bb * 1024 + kvg] != 0;
#pragma unroll
            for (int r = 0; r < 4; r++) {
                const int qg = qbase + w * 16 + lg * 4 + r;
                if (kvg > qg || padm) s[jt][r] = -1e30f;
            }
        }
        // online softmax (row groups of 16 lanes)
        float alpha[4];
#pragma unroll
        for (int r = 0; r < 4; r++) {
            float mx = fmaxf(fmaxf(s[0][r], s[1][r]), fmaxf(s[2][r], s[3][r]));
#pragma unroll
            for (int mk = 8; mk >= 1; mk >>= 1) mx = fmaxf(mx, __shfl_xor(mx, mk));
            const float mn = fmaxf(mrow[r], mx);
            alpha[r] = __expf(mrow[r] - mn);
            mrow[r] = mn;
        }
#pragma unroll
        for (int jt = 0; jt < 4; jt++)
#pragma unroll
            for (int r = 0; r < 4; r++)
                s[jt][r] = __expf(s[jt][r] - mrow[r]);
#pragma unroll
        for (int r = 0; r < 4; r++) {
            float sm = s[0][r] + s[1][r] + s[2][r] + s[3][r];
#pragma unroll
            for (int mk = 8; mk >= 1; mk >>= 1) sm += __shfl_xor(sm, mk);
            lsum[r] = lsum[r] * alpha[r] + sm;
        }
#pragma unroll
        for (int ct = 0; ct < 4; ct++)
#pragma unroll
            for (int r = 0; r < 4; r++)
                oacc[ct][r] *= alpha[r];
        // P -> LDS (per wave), swizzled, convert to A-fragment layout
#pragma unroll
        for (int jt = 0; jt < 4; jt++)
#pragma unroll
            for (int r = 0; r < 4; r++) {
                const int prow = lg * 4 + r;
                const int kvc = jt * 16 + lrow;
                Ps[w][prow * 64 + (((kvc >> 3) ^ (prow & 7)) * 8) + (kvc & 7)] = (bf16_t)s[jt][r];
            }
        // PV (same-wave LDS RAW; compiler orders DS ops within a wave)
#pragma unroll
        for (int ks = 0; ks < 2; ks++) {
            bf16x8 pa = *reinterpret_cast<const bf16x8*>(
                &Ps[w][lrow * 64 + (((ks * 4 + lg) ^ (lrow & 7)) * 8)]);
#pragma unroll
            for (int ct = 0; ct < 4; ct++) {
                const int vr = ct * 16 + lrow;
                bf16x8 vb = *reinterpret_cast<const bf16x8*>(
                    Vs + vr * 64 + (((ks * 4 + lg) ^ (vr & 7)) * 8));
                oacc[ct] = __builtin_amdgcn_mfma_f32_16x16x32_bf16(pa, vb, oacc[ct], 0, 0, 0);
            }
        }
    }
    // epilogue: o[b][n][h*64+ch] bf16
#pragma unroll
    for (int ct = 0; ct < 4; ct++) {
#pragma unroll
        for (int r = 0; r < 4; r++) {
            const int qg = qbase + w * 16 + lg * 4 + r;
            const float val = oacc[ct][r] / lsum[r];
            o[((size_t)bb * 1024 + qg) * 1024 + hh * 64 + ct * 16 + lrow] = (bf16_t)val;
        }
    }
}

extern "C" void kernel_launch(void* const* d_in, const int* in_sizes, int n_in,
                              void* d_out, int out_size, void* d_ws, size_t ws_size,
                              hipStream_t stream) {
    const float* x    = (const float*)d_in[0];
    const float* ln1g = (const float*)d_in[1];
    const float* ln1b = (const float*)d_in[2];
    const float* Wq   = (const float*)d_in[3];
    const float* bq   = (const float*)d_in[4];
    const float* Wk   = (const float*)d_in[5];
    const float* bk   = (const float*)d_in[6];
    const float* Wv   = (const float*)d_in[7];
    const float* bv   = (const float*)d_in[8];
    const float* Wo   = (const float*)d_in[9];
    const float* bo   = (const float*)d_in[10];
    const float* ln2g = (const float*)d_in[11];
    const float* ln2b = (const float*)d_in[12];
    const float* W1   = (const float*)d_in[13];
    const float* b1   = (const float*)d_in[14];
    const float* W2   = (const float*)d_in[15];
    const float* b2   = (const float*)d_in[16];
    const unsigned char* pad = (const unsigned char*)d_in[17];

    char* ws = (char*)d_ws;
    const size_t MB = 1024 * 1024;
    bf16_t* WqkvT = (bf16_t*)(ws + 0 * MB);   // 3072x1024 bf16 = 6MB
    bf16_t* WoT = (bf16_t*)(ws + 6 * MB);     // 2MB
    bf16_t* W1T = (bf16_t*)(ws + 8 * MB);     // 8MB
    bf16_t* W2T = (bf16_t*)(ws + 16 * MB);    // 8MB
    bf16_t* h   = (bf16_t*)(ws + 24 * MB);    // 8MB
    bf16_t* qb  = (bf16_t*)(ws + 32 * MB);    // 8MB
    bf16_t* kb  = (bf16_t*)(ws + 40 * MB);    // 8MB
    bf16_t* vb  = (bf16_t*)(ws + 48 * MB);    // 8MB (transposed [bh][ch][n])
    bf16_t* hid = (bf16_t*)(ws + 24 * MB);    // 32MB, overlays h,q,k,v (dead by then)
    bf16_t* ob  = (bf16_t*)(ws + 56 * MB);    // 8MB
    bf16_t* m2  = (bf16_t*)(ws + 56 * MB);    // overlays ob (dead by then)
    float*  x2  = (float*)(ws + 64 * MB);     // 16MB; total 80MB

    const dim3 blk(256);
    // weight transposes (f32 -> bf16, W^T); q/k/v packed into one 3072-row BT
    k_transpose_bf16<<<dim3(32, 32), blk, 0, stream>>>(Wq, WqkvT, 1024, 1024);
    k_transpose_bf16<<<dim3(32, 32), blk, 0, stream>>>(Wk, WqkvT + 1024 * 1024, 1024, 1024);
    k_transpose_bf16<<<dim3(32, 32), blk, 0, stream>>>(Wv, WqkvT + 2048 * 1024, 1024, 1024);
    k_transpose_bf16<<<dim3(32, 32), blk, 0, stream>>>(Wo, WoT, 1024, 1024);
    k_transpose_bf16<<<dim3(128, 32), blk, 0, stream>>>(W1, W1T, 1024, 4096);
    k_transpose_bf16<<<dim3(32, 128), blk, 0, stream>>>(W2, W2T, 4096, 1024);
    // LN1
    k_layernorm<<<4096, blk, 0, stream>>>(x, ln1g, ln1b, h);
    // fused QKV projection (q scaled by 0.125 in epilogue; V written transposed)
    k_gemm<EPI_QKV, 128, 128><<<dim3(24, 32), blk, 0, stream>>>(
        h, WqkvT, bq, bk, bv, nullptr, nullptr, qb, kb, vb, 4096, 3072, 1024);
    // attention
    k_attn<<<dim3(16, 64), blk, 0, stream>>>(qb, kb, vb, pad, ob);
    // O projection + residual -> x2 (f32); BM=64 -> 512 blocks (2/CU)
    k_gemm<EPI_RESID, 64, 128><<<dim3(8, 64), blk, 0, stream>>>(
        ob, WoT, bo, nullptr, nullptr, x, x2, nullptr, nullptr, nullptr, 4096, 1024, 1024);
    // LN2
    k_layernorm<<<4096, blk, 0, stream>>>(x2, ln2g, ln2b, m2);
    // MLP
    k_gemm<EPI_GELU, 128, 128><<<dim3(32, 32), blk, 0, stream>>>(
        m2, W1T, b1, nullptr, nullptr, nullptr, nullptr, hid, nullptr, nullptr, 4096, 4096, 1024);
    // final: M=4096, N=1024, K=4096; BM=64 -> 512 blocks (2/CU)
    k_gemm<EPI_RESID, 64, 128><<<dim3(8, 64), blk, 0, stream>>>(
        hid, W2T, b2, nullptr, nullptr, x2, (float*)d_out, nullptr, nullptr, nullptr, 4096, 1024, 4096);
}